// Round 1
// baseline (191.251 us; speedup 1.0000x reference)
//
#include <hip/hip_runtime.h>

#define NH 8
#define DCM 64
#define NB 2
#define NS 512
#define NL 384
#define LN_EPS 1e-5f
#define INV_SQRT_C 0.35355339059327379f

__device__ __forceinline__ float4 ld4(const float* p) {
  return *reinterpret_cast<const float4*>(p);
}

// ---------------------------------------------------------------------------
// Kernel 1: one workgroup per (b,l) column. Computes global query, folded
// qk vectors, streaming (unnormalized) softmax accumulation of sum_s p*x,
// then out_global (og) via wv.
// ---------------------------------------------------------------------------
__global__ __launch_bounds__(256) void col_attn(
    const float* __restrict__ m, const float* __restrict__ msk,
    const float* __restrict__ lnw, const float* __restrict__ lnb,
    const float* __restrict__ wq, const float* __restrict__ wk,
    const float* __restrict__ wv, float* __restrict__ og)
{
  const int col = blockIdx.x;          // b*NL + l
  const int b = col / NL, l = col % NL;
  const int tid = threadIdx.x;
  const int wave = tid >> 6, lane = tid & 63;
  const int qd = lane & 15;            // quad of 4 channels: cm = qd*4..qd*4+3
  const int rsub = lane >> 4;          // row sub-index within wave iteration

  __shared__ float mask_s[NS];
  __shared__ float red[4*DCM];
  __shared__ float dred[4];
  __shared__ float qin[DCM];
  __shared__ float q_s[DCM];
  __shared__ float qk_s[NH*DCM];
  __shared__ float xred[4*NH*DCM];
  __shared__ float smred[4*NH];
  __shared__ float xat[NH*DCM];

  for (int i = tid; i < NS; i += 256)
    mask_s[i] = msk[(b*NS + i)*NL + l];

  float lw[4], lb[4];
#pragma unroll
  for (int k = 0; k < 4; ++k) { lw[k] = lnw[qd*4+k]; lb[k] = lnb[qd*4+k]; }

  const float* mcol = m + ((size_t)b*NS*NL + l)*DCM + qd*4;  // + s*NL*DCM
  __syncthreads();

  // ---------- pass 1: masked sum of LN(x) over s -> q_input ----------
  float qacc[4] = {0.f,0.f,0.f,0.f};
  float dacc = 0.f;
  {
    int s = wave*4 + rsub;
    float4 f = ld4(mcol + (size_t)s*NL*DCM);
    for (int it = 0; it < 32; ++it) {
      float4 cur = f;
      int sn = s + 16;
      if (it < 31) f = ld4(mcol + (size_t)sn*NL*DCM);  // depth-2 prefetch
      float s1 = cur.x+cur.y+cur.z+cur.w;
      float s2 = cur.x*cur.x+cur.y*cur.y+cur.z*cur.z+cur.w*cur.w;
#pragma unroll
      for (int o = 1; o <= 8; o <<= 1) { s1 += __shfl_xor(s1,o); s2 += __shfl_xor(s2,o); }
      float mu = s1 * 0.015625f;
      float rs = rsqrtf(s2*0.015625f - mu*mu + LN_EPS);
      float mk = mask_s[s];
      float x0 = (cur.x-mu)*rs*lw[0]+lb[0];
      float x1 = (cur.y-mu)*rs*lw[1]+lb[1];
      float x2 = (cur.z-mu)*rs*lw[2]+lb[2];
      float x3 = (cur.w-mu)*rs*lw[3]+lb[3];
      qacc[0] += x0*mk; qacc[1] += x1*mk; qacc[2] += x2*mk; qacc[3] += x3*mk;
      dacc += mk;
      s = sn;
    }
  }
#pragma unroll
  for (int k = 0; k < 4; ++k) {
    qacc[k] += __shfl_xor(qacc[k],16); qacc[k] += __shfl_xor(qacc[k],32);
  }
  dacc += __shfl_xor(dacc,16); dacc += __shfl_xor(dacc,32);
  if (lane < 16) {
    float4 t; t.x=qacc[0]; t.y=qacc[1]; t.z=qacc[2]; t.w=qacc[3];
    *reinterpret_cast<float4*>(&red[wave*DCM + lane*4]) = t;
  }
  if (lane == 0) dred[wave] = dacc;
  __syncthreads();

  if (tid < DCM) {
    float dn = fmaxf(dred[0]+dred[1]+dred[2]+dred[3], 1.0f);
    qin[tid] = (red[tid]+red[DCM+tid]+red[2*DCM+tid]+red[3*DCM+tid]) / dn;
  }
  __syncthreads();
  // q = q_input @ wq
  if (tid < DCM) {
    float a = 0.f;
    for (int j = 0; j < DCM; ++j) a += qin[j] * wq[j*DCM + tid];
    q_s[tid] = a;
  }
  __syncthreads();
  // qk[h][cm] = sum_c q[h][c] * wk[cm][h*8+c] * 1/sqrt(C)
  for (int idx = tid; idx < NH*DCM; idx += 256) {
    int h = idx >> 6, cm = idx & 63;
    float a = 0.f;
#pragma unroll
    for (int c = 0; c < 8; ++c) a += q_s[h*8+c] * wk[cm*DCM + h*8 + c];
    qk_s[idx] = a * INV_SQRT_C;
  }
  __syncthreads();

  float qkq[NH][4];
#pragma unroll
  for (int h = 0; h < NH; ++h) {
    float4 t = ld4(&qk_s[h*DCM + qd*4]);
    qkq[h][0]=t.x; qkq[h][1]=t.y; qkq[h][2]=t.z; qkq[h][3]=t.w;
  }

  // ---------- pass 2: logits + unnormalized softmax accumulation ----------
  float sm[NH], xa[NH][4];
#pragma unroll
  for (int h = 0; h < NH; ++h) {
    sm[h]=0.f; xa[h][0]=0.f; xa[h][1]=0.f; xa[h][2]=0.f; xa[h][3]=0.f;
  }
  {
    int s = wave*4 + rsub;
    float4 f = ld4(mcol + (size_t)s*NL*DCM);
    for (int it = 0; it < 32; ++it) {
      float4 cur = f;
      int sn = s + 16;
      if (it < 31) f = ld4(mcol + (size_t)sn*NL*DCM);
      float s1 = cur.x+cur.y+cur.z+cur.w;
      float s2 = cur.x*cur.x+cur.y*cur.y+cur.z*cur.z+cur.w*cur.w;
#pragma unroll
      for (int o = 1; o <= 8; o <<= 1) { s1 += __shfl_xor(s1,o); s2 += __shfl_xor(s2,o); }
      float mu = s1 * 0.015625f;
      float rs = rsqrtf(s2*0.015625f - mu*mu + LN_EPS);
      float mk = mask_s[s];
      float x0 = (cur.x-mu)*rs*lw[0]+lb[0];
      float x1 = (cur.y-mu)*rs*lw[1]+lb[1];
      float x2 = (cur.z-mu)*rs*lw[2]+lb[2];
      float x3 = (cur.w-mu)*rs*lw[3]+lb[3];
      float pt[NH];
#pragma unroll
      for (int h = 0; h < NH; ++h)
        pt[h] = qkq[h][0]*x0 + qkq[h][1]*x1 + qkq[h][2]*x2 + qkq[h][3]*x3;
#pragma unroll
      for (int o = 1; o <= 8; o <<= 1) {
#pragma unroll
        for (int h = 0; h < NH; ++h) pt[h] += __shfl_xor(pt[h], o);
      }
      // logits are tiny (global query is a mean) -> exp without max-sub is
      // safe; masked rows contribute p = 0 exactly (mk in {0,1}).
#pragma unroll
      for (int h = 0; h < NH; ++h) {
        float p = mk * __expf(pt[h]);
        sm[h] += p;
        xa[h][0] += p*x0; xa[h][1] += p*x1; xa[h][2] += p*x2; xa[h][3] += p*x3;
      }
      s = sn;
    }
  }
#pragma unroll
  for (int h = 0; h < NH; ++h) {
    sm[h] += __shfl_xor(sm[h],16); sm[h] += __shfl_xor(sm[h],32);
#pragma unroll
    for (int k = 0; k < 4; ++k) {
      xa[h][k] += __shfl_xor(xa[h][k],16); xa[h][k] += __shfl_xor(xa[h][k],32);
    }
  }
  if (lane < 16) {
#pragma unroll
    for (int h = 0; h < NH; ++h) {
      float4 t; t.x=xa[h][0]; t.y=xa[h][1]; t.z=xa[h][2]; t.w=xa[h][3];
      *reinterpret_cast<float4*>(&xred[(wave*NH + h)*DCM + lane*4]) = t;
    }
  }
  if (lane == 0) {
#pragma unroll
    for (int h = 0; h < NH; ++h) smred[wave*NH + h] = sm[h];
  }
  __syncthreads();
  for (int idx = tid; idx < NH*DCM; idx += 256)
    xat[idx] = xred[idx] + xred[NH*DCM+idx] + xred[2*NH*DCM+idx] + xred[3*NH*DCM+idx];
  __syncthreads();
  // og[h][c] = (sum_cm xat[h][cm] * wv[cm][h*8+c]) / sum_p
  if (tid < DCM) {
    int h = tid >> 3, c = tid & 7;
    float smT = fmaxf(smred[h]+smred[NH+h]+smred[2*NH+h]+smred[3*NH+h], 1e-30f);
    float a = 0.f;
    for (int cm = 0; cm < DCM; ++cm) a += xat[h*DCM + cm] * wv[cm*DCM + h*8 + c];
    og[col*DCM + tid] = a / smT;
  }
}

// ---------------------------------------------------------------------------
// Kernel 2: out = (sigmoid(LN(m)@wg + bg) * og[b,l]) @ wo + bo, * mask.
// 64 consecutive flat rows per WG (same b,s since 384 % 64 == 0).
// Register-blocked 4x4 outer-product GEMMs from LDS (xT stride 68 = pad).
// ---------------------------------------------------------------------------
__global__ __launch_bounds__(256) void out_kernel(
    const float* __restrict__ m, const float* __restrict__ msk,
    const float* __restrict__ lnw, const float* __restrict__ lnb,
    const float* __restrict__ wg, const float* __restrict__ bg,
    const float* __restrict__ wo, const float* __restrict__ bo,
    const float* __restrict__ og, float* __restrict__ out)
{
  const int tid = threadIdx.x;
  const size_t tile0 = (size_t)blockIdx.x * 64;
  const int bidx = (int)(tile0 / ((size_t)NS*NL));
  const int rem  = (int)(tile0 % ((size_t)NS*NL));
  const int l0 = rem % NL;
  const int ogbase = bidx*NL + l0;

  __shared__ float xT[64*68];
  __shared__ float wgs[64*64];
  __shared__ float wos[64*64];
  __shared__ float maskv[64];

  for (int i = tid; i < 1024; i += 256) {
    reinterpret_cast<float4*>(wgs)[i] = reinterpret_cast<const float4*>(wg)[i];
    reinterpret_cast<float4*>(wos)[i] = reinterpret_cast<const float4*>(wo)[i];
  }

  const int qd = tid & 15, rg = tid >> 4;
  float lw[4], lb[4];
#pragma unroll
  for (int k = 0; k < 4; ++k) { lw[k] = lnw[qd*4+k]; lb[k] = lnb[qd*4+k]; }

#pragma unroll
  for (int p = 0; p < 4; ++p) {
    const int r = p*16 + rg;
    float4 f = ld4(&m[(tile0 + r)*DCM + qd*4]);
    float s1 = f.x+f.y+f.z+f.w;
    float s2 = f.x*f.x+f.y*f.y+f.z*f.z+f.w*f.w;
#pragma unroll
    for (int o = 1; o <= 8; o <<= 1) { s1 += __shfl_xor(s1,o); s2 += __shfl_xor(s2,o); }
    float mu = s1*0.015625f;
    float rs = rsqrtf(s2*0.015625f - mu*mu + LN_EPS);
    xT[(qd*4+0)*68 + r] = (f.x-mu)*rs*lw[0]+lb[0];
    xT[(qd*4+1)*68 + r] = (f.y-mu)*rs*lw[1]+lb[1];
    xT[(qd*4+2)*68 + r] = (f.z-mu)*rs*lw[2]+lb[2];
    xT[(qd*4+3)*68 + r] = (f.w-mu)*rs*lw[3]+lb[3];
    if (qd == 0) maskv[r] = msk[tile0 + r];
  }
  __syncthreads();

  const int c0 = (tid & 15)*4;
  const int r0 = (tid >> 4)*4;

  float acc[4][4] = {};
#pragma unroll
  for (int j = 0; j < 64; ++j) {
    float4 a = ld4(&xT[j*68 + r0]);
    float4 w4 = ld4(&wgs[j*64 + c0]);
    const float av[4] = {a.x,a.y,a.z,a.w};
    const float wv4[4] = {w4.x,w4.y,w4.z,w4.w};
#pragma unroll
    for (int rr = 0; rr < 4; ++rr)
#pragma unroll
      for (int cc = 0; cc < 4; ++cc) acc[rr][cc] += av[rr]*wv4[cc];
  }

  float4 bg4 = ld4(&bg[c0]);
  const float bgv[4] = {bg4.x,bg4.y,bg4.z,bg4.w};
  float a2[4][4];
#pragma unroll
  for (int rr = 0; rr < 4; ++rr) {
    float4 ogv = ld4(&og[(size_t)(ogbase + r0 + rr)*DCM + c0]);
    const float ogt[4] = {ogv.x,ogv.y,ogv.z,ogv.w};
#pragma unroll
    for (int cc = 0; cc < 4; ++cc) {
      float xg = acc[rr][cc] + bgv[cc];
      float gg = 1.0f / (1.0f + __expf(-xg));
      a2[rr][cc] = gg * ogt[cc];
    }
  }
  __syncthreads();                    // all xT reads done before overwrite
#pragma unroll
  for (int rr = 0; rr < 4; ++rr)
#pragma unroll
    for (int cc = 0; cc < 4; ++cc)
      xT[(c0+cc)*68 + (r0+rr)] = a2[rr][cc];
  __syncthreads();

  float acc2[4][4] = {};
#pragma unroll
  for (int c = 0; c < 64; ++c) {
    float4 a = ld4(&xT[c*68 + r0]);
    float4 w4 = ld4(&wos[c*64 + c0]);
    const float av[4] = {a.x,a.y,a.z,a.w};
    const float wv4[4] = {w4.x,w4.y,w4.z,w4.w};
#pragma unroll
    for (int rr = 0; rr < 4; ++rr)
#pragma unroll
      for (int cc = 0; cc < 4; ++cc) acc2[rr][cc] += av[rr]*wv4[cc];
  }

  float4 bo4 = ld4(&bo[c0]);
  const float bov[4] = {bo4.x,bo4.y,bo4.z,bo4.w};
#pragma unroll
  for (int rr = 0; rr < 4; ++rr) {
    const float mk = maskv[r0+rr];
    float4 o;
    o.x = (acc2[rr][0] + bov[0])*mk;
    o.y = (acc2[rr][1] + bov[1])*mk;
    o.z = (acc2[rr][2] + bov[2])*mk;
    o.w = (acc2[rr][3] + bov[3])*mk;
    *reinterpret_cast<float4*>(&out[(tile0 + r0 + rr)*DCM + c0]) = o;
  }
}

extern "C" void kernel_launch(void* const* d_in, const int* in_sizes, int n_in,
                              void* d_out, int out_size, void* d_ws, size_t ws_size,
                              hipStream_t stream) {
  (void)in_sizes; (void)n_in; (void)out_size; (void)ws_size;
  const float* m   = (const float*)d_in[0];
  const float* msk = (const float*)d_in[1];
  const float* lnw = (const float*)d_in[2];
  const float* lnb = (const float*)d_in[3];
  const float* wq  = (const float*)d_in[4];
  const float* wk  = (const float*)d_in[5];
  const float* wv  = (const float*)d_in[6];
  const float* wg  = (const float*)d_in[7];
  const float* bg  = (const float*)d_in[8];
  const float* wo  = (const float*)d_in[9];
  const float* bo  = (const float*)d_in[10];
  float* og  = (float*)d_ws;                     // [B*L, 64] = 196,608 floats
  float* out = (float*)d_out;

  col_attn<<<dim3(NB*NL), dim3(256), 0, stream>>>(m, msk, lnw, lnb, wq, wk, wv, og);
  out_kernel<<<dim3((NB*NS*NL)/64), dim3(256), 0, stream>>>(
      m, msk, lnw, lnb, wg, bg, wo, bo, og, out);
}

// Round 3
// 100.809 us; speedup vs baseline: 1.8972x; 1.8972x over previous
//
#include <hip/hip_runtime.h>

#define NH 8
#define DCM 64
#define NB 2
#define NS 512
#define NL 384
#define LN_EPS 1e-5f
#define INV_SQRT_C 0.35355339059327379f

typedef __attribute__((ext_vector_type(8))) short short8v;   // 8 bf16 (4 VGPRs)
typedef __attribute__((ext_vector_type(4))) float f32x4;

__device__ __forceinline__ float4 ld4(const float* p) {
  return *reinterpret_cast<const float4*>(p);
}
__device__ __forceinline__ unsigned short f2bf(float f) {
  unsigned int b = __float_as_uint(f);
  b += 0x7FFFu + ((b >> 16) & 1u);          // round-to-nearest-even
  return (unsigned short)(b >> 16);
}
__device__ __forceinline__ float bf2f(unsigned short u) {
  return __uint_as_float(((unsigned int)u) << 16);
}

// ---------------------------------------------------------------------------
// Prep: wt[0..4095] = wg^T as bf16 [n][k]; wt[4096..8191] = wo^T as bf16.
// B-frag for mfma_16x16x32 wants 8 contiguous k at fixed n -> one 16B load.
// ---------------------------------------------------------------------------
__global__ void prep_weights(const float* __restrict__ wg,
                             const float* __restrict__ wo,
                             unsigned short* __restrict__ wt) {
  int i = blockIdx.x * 256 + threadIdx.x;
  if (i < 4096) {
    int n = i >> 6, k = i & 63;
    wt[i]        = f2bf(wg[k * DCM + n]);
    wt[4096 + i] = f2bf(wo[k * DCM + n]);
  }
}

// ---------------------------------------------------------------------------
// Fused: one WG per (b,l) column. m read ONCE from HBM.
//   P1: stream+LN -> x bf16 in LDS (XOR-swizzled) + masked sum -> q -> qk
//   P2: VALU attention (logits, exp, sum p*x) from LDS x -> og
//   P3: MFMA gating+output GEMMs -> out
// ---------------------------------------------------------------------------
__global__ __launch_bounds__(256) void fused(
    const float* __restrict__ m, const float* __restrict__ msk,
    const float* __restrict__ lnw, const float* __restrict__ lnb,
    const float* __restrict__ wq, const float* __restrict__ wk,
    const float* __restrict__ wv, const unsigned short* __restrict__ wt,
    const float* __restrict__ bg, const float* __restrict__ bo,
    float* __restrict__ out)
{
  const int col = blockIdx.x;              // b*NL + l
  const int b = col / NL, l = col % NL;
  const int tid = threadIdx.x;
  const int wave = tid >> 6, lane = tid & 63;

  __shared__ __align__(16) unsigned short x_lds[NS * DCM];   // 64 KB, swizzled
  __shared__ unsigned short mask_s[NS];                      // 1 KB (0/1 exact)
  __shared__ __align__(16) float red[4 * DCM];
  __shared__ float dred[4];
  __shared__ float qin[DCM];
  __shared__ float q_s[DCM];
  __shared__ __align__(16) float qk_s[NH * DCM];
  __shared__ __align__(16) float xred_f[4 * NH * DCM];       // P2; aliased in P3
  __shared__ float smred[4 * NH];
  __shared__ float xat[NH * DCM];
  __shared__ float og_s[DCM];

  for (int i = tid; i < NS; i += 256)
    mask_s[i] = f2bf(msk[(b * NS + i) * NL + l]);

  // ---------------- Phase 1: stream m once, LN, x->LDS bf16, masked sum ----
  const int c8 = lane & 7;          // channel block: cm = c8*8 .. c8*8+7
  const int r8 = lane >> 3;         // row within 8-row group
  const float* mbase = m + ((size_t)b * NS * NL + l) * DCM + c8 * 8;
  float lw8[8], lb8[8];
#pragma unroll
  for (int k = 0; k < 8; ++k) { lw8[k] = lnw[c8 * 8 + k]; lb8[k] = lnb[c8 * 8 + k]; }
  __syncthreads();                  // mask_s ready

  float qacc[8] = {0.f,0.f,0.f,0.f,0.f,0.f,0.f,0.f};
  float dacc = 0.f;
  const int rowbase = wave * 128;
  float4 fA0, fA1, fB0, fB1;
  {
    const float* p0 = mbase + (size_t)(rowbase + r8) * NL * DCM;
    fA0 = ld4(p0); fA1 = ld4(p0 + 4);
  }
  for (int it = 0; it < 16; ++it) {
    const int s = rowbase + it * 8 + r8;
    if (it < 15) {
      const float* pn = mbase + (size_t)(s + 8) * NL * DCM;
      fB0 = ld4(pn); fB1 = ld4(pn + 4);
    }
    float xv[8] = {fA0.x, fA0.y, fA0.z, fA0.w, fA1.x, fA1.y, fA1.z, fA1.w};
    float s1 = 0.f, s2 = 0.f;
#pragma unroll
    for (int k = 0; k < 8; ++k) { s1 += xv[k]; s2 += xv[k] * xv[k]; }
#pragma unroll
    for (int o = 1; o <= 4; o <<= 1) { s1 += __shfl_xor(s1, o); s2 += __shfl_xor(s2, o); }
    const float mu = s1 * 0.015625f;
    const float rs = rsqrtf(s2 * 0.015625f - mu * mu + LN_EPS);
    const float mk = bf2f(mask_s[s]);
    short8v xpack;
#pragma unroll
    for (int k = 0; k < 8; ++k) {
      float xn = (xv[k] - mu) * rs * lw8[k] + lb8[k];
      xpack[k] = (short)f2bf(xn);
      qacc[k] += xn * mk;
    }
    dacc += mk;
    // swizzled store: elem = s*64 + ((c8*8) ^ ((s&7)<<3))
    const int el = s * DCM + ((c8 * 8) ^ ((s & 7) << 3));
    *reinterpret_cast<short8v*>(&x_lds[el]) = xpack;
    fA0 = fB0; fA1 = fB1;
  }
#pragma unroll
  for (int o = 8; o <= 32; o <<= 1) {
#pragma unroll
    for (int k = 0; k < 8; ++k) qacc[k] += __shfl_xor(qacc[k], o);
    dacc += __shfl_xor(dacc, o);
  }
  if (lane < 8) {
    float4 t0; t0.x = qacc[0]; t0.y = qacc[1]; t0.z = qacc[2]; t0.w = qacc[3];
    float4 t1; t1.x = qacc[4]; t1.y = qacc[5]; t1.z = qacc[6]; t1.w = qacc[7];
    *reinterpret_cast<float4*>(&red[wave * DCM + lane * 8])     = t0;
    *reinterpret_cast<float4*>(&red[wave * DCM + lane * 8 + 4]) = t1;
  }
  // NOTE: xor-reduce over offsets {8,16,32} sums over r8 only -> each of the
  // wave's 128 rows is counted exactly ONCE (c8 replicas are never merged).
  // The previous *0.125f "correction" was an 8x denominator bug.
  if (lane == 0) dred[wave] = dacc;
  __syncthreads();

  if (tid < DCM) {
    float dn = fmaxf(dred[0] + dred[1] + dred[2] + dred[3], 1.0f);
    qin[tid] = (red[tid] + red[DCM + tid] + red[2 * DCM + tid] + red[3 * DCM + tid]) / dn;
  }
  __syncthreads();
  if (tid < DCM) {
    float a = 0.f;
    for (int j = 0; j < DCM; ++j) a += qin[j] * wq[j * DCM + tid];
    q_s[tid] = a;
  }
  __syncthreads();
  for (int idx = tid; idx < NH * DCM; idx += 256) {
    int h = idx >> 6, cm = idx & 63;
    float a = 0.f;
#pragma unroll
    for (int c = 0; c < 8; ++c) a += q_s[h * 8 + c] * wk[cm * DCM + h * 8 + c];
    qk_s[idx] = a * INV_SQRT_C;
  }
  __syncthreads();

  // ---------------- Phase 2: attention from LDS x (VALU, verified path) ----
  const int qd = lane & 15, rsub = lane >> 4;
  float qkq[NH][4];
#pragma unroll
  for (int h = 0; h < NH; ++h) {
    float4 t = ld4(&qk_s[h * DCM + qd * 4]);
    qkq[h][0] = t.x; qkq[h][1] = t.y; qkq[h][2] = t.z; qkq[h][3] = t.w;
  }
  float sm[NH], xa[NH][4];
#pragma unroll
  for (int h = 0; h < NH; ++h) {
    sm[h] = 0.f; xa[h][0] = 0.f; xa[h][1] = 0.f; xa[h][2] = 0.f; xa[h][3] = 0.f;
  }
  for (int it = 0; it < 32; ++it) {
    const int s = wave * 4 + rsub + it * 16;
    const int el = s * DCM + ((qd * 4) ^ ((s & 7) << 3));
    short4 xv4 = *reinterpret_cast<const short4*>(&x_lds[el]);
    const float x0 = bf2f((unsigned short)xv4.x);
    const float x1 = bf2f((unsigned short)xv4.y);
    const float x2 = bf2f((unsigned short)xv4.z);
    const float x3 = bf2f((unsigned short)xv4.w);
    const float mk = bf2f(mask_s[s]);
    float pt[NH];
#pragma unroll
    for (int h = 0; h < NH; ++h)
      pt[h] = qkq[h][0] * x0 + qkq[h][1] * x1 + qkq[h][2] * x2 + qkq[h][3] * x3;
#pragma unroll
    for (int o = 1; o <= 8; o <<= 1) {
#pragma unroll
      for (int h = 0; h < NH; ++h) pt[h] += __shfl_xor(pt[h], o);
    }
    // logits are tiny (global query is a mean) -> no max-sub needed;
    // masked rows contribute p = 0 exactly.
#pragma unroll
    for (int h = 0; h < NH; ++h) {
      float p = mk * __expf(pt[h]);
      sm[h] += p;
      xa[h][0] += p * x0; xa[h][1] += p * x1; xa[h][2] += p * x2; xa[h][3] += p * x3;
    }
  }
#pragma unroll
  for (int h = 0; h < NH; ++h) {
    sm[h] += __shfl_xor(sm[h], 16); sm[h] += __shfl_xor(sm[h], 32);
#pragma unroll
    for (int k = 0; k < 4; ++k) {
      xa[h][k] += __shfl_xor(xa[h][k], 16); xa[h][k] += __shfl_xor(xa[h][k], 32);
    }
  }
  if (lane < 16) {
#pragma unroll
    for (int h = 0; h < NH; ++h) {
      float4 t; t.x = xa[h][0]; t.y = xa[h][1]; t.z = xa[h][2]; t.w = xa[h][3];
      *reinterpret_cast<float4*>(&xred_f[(wave * NH + h) * DCM + lane * 4]) = t;
    }
  }
  if (lane == 0) {
#pragma unroll
    for (int h = 0; h < NH; ++h) smred[wave * NH + h] = sm[h];
  }
  __syncthreads();
  for (int idx = tid; idx < NH * DCM; idx += 256)
    xat[idx] = xred_f[idx] + xred_f[NH * DCM + idx] + xred_f[2 * NH * DCM + idx]
             + xred_f[3 * NH * DCM + idx];
  __syncthreads();
  if (tid < DCM) {
    int h = tid >> 3, c = tid & 7;
    float smT = fmaxf(smred[h] + smred[NH + h] + smred[2 * NH + h] + smred[3 * NH + h], 1e-30f);
    float a = 0.f;
    for (int cm = 0; cm < DCM; ++cm) a += xat[h * DCM + cm] * wv[cm * DCM + h * 8 + c];
    og_s[tid] = a / smT;
  }
  __syncthreads();   // og ready; xred_f dead -> reuse as a2t below

  // ---------------- Phase 3: MFMA gating + output GEMMs --------------------
  unsigned short* a2t = reinterpret_cast<unsigned short*>(xred_f);
  const int bcol = lane & 15;        // n within 16-tile; doubles as A-row idx
  const int kg = lane >> 4;          // k-group
  short8v wgB[4][2], woB[4][2];
  float bgv[4], bov[4], ogv[4];
#pragma unroll
  for (int nt = 0; nt < 4; ++nt) {
    const int ncol = nt * 16 + bcol;
#pragma unroll
    for (int kw = 0; kw < 2; ++kw) {
      wgB[nt][kw] = *reinterpret_cast<const short8v*>(&wt[ncol * DCM + kw * 32 + kg * 8]);
      woB[nt][kw] = *reinterpret_cast<const short8v*>(&wt[4096 + ncol * DCM + kw * 32 + kg * 8]);
    }
    bgv[nt] = bg[ncol]; bov[nt] = bo[ncol]; ogv[nt] = og_s[ncol];
  }
  const size_t outbase = ((size_t)b * NS * NL + l) * DCM;
  unsigned short* a2w = &a2t[wave * 16 * DCM];

  for (int t = 0; t < 8; ++t) {
    const int arow = wave * 128 + t * 16 + bcol;
    const int swz = (arow & 7) << 3;
    short8v a0 = *reinterpret_cast<const short8v*>(&x_lds[arow * DCM + ((kg * 8) ^ swz)]);
    short8v a1 = *reinterpret_cast<const short8v*>(&x_lds[arow * DCM + ((32 + kg * 8) ^ swz)]);
    f32x4 accG[4];
#pragma unroll
    for (int nt = 0; nt < 4; ++nt) {
      accG[nt] = (f32x4){0.f, 0.f, 0.f, 0.f};
      accG[nt] = __builtin_amdgcn_mfma_f32_16x16x32_bf16(a0, wgB[nt][0], accG[nt], 0, 0, 0);
      accG[nt] = __builtin_amdgcn_mfma_f32_16x16x32_bf16(a1, wgB[nt][1], accG[nt], 0, 0, 0);
    }
    // sigmoid gate * og, write transposed bf16 (swizzled) to wave scratch
#pragma unroll
    for (int nt = 0; nt < 4; ++nt) {
      const int cc = nt * 16 + bcol;
#pragma unroll
      for (int r = 0; r < 4; ++r) {
        const int r2 = kg * 4 + r;                 // C-layout row
        float gx = accG[nt][r] + bgv[nt];
        float g = 1.0f / (1.0f + __expf(-gx));
        a2w[r2 * DCM + (cc ^ ((r2 & 7) << 3))] = f2bf(g * ogv[nt]);
      }
    }
    short8v b0 = *reinterpret_cast<const short8v*>(
        &a2w[bcol * DCM + ((kg * 8) ^ ((bcol & 7) << 3))]);
    short8v b1 = *reinterpret_cast<const short8v*>(
        &a2w[bcol * DCM + ((32 + kg * 8) ^ ((bcol & 7) << 3))]);
    f32x4 accO[4];
#pragma unroll
    for (int nt = 0; nt < 4; ++nt) {
      accO[nt] = (f32x4){0.f, 0.f, 0.f, 0.f};
      accO[nt] = __builtin_amdgcn_mfma_f32_16x16x32_bf16(b0, woB[nt][0], accO[nt], 0, 0, 0);
      accO[nt] = __builtin_amdgcn_mfma_f32_16x16x32_bf16(b1, woB[nt][1], accO[nt], 0, 0, 0);
    }
#pragma unroll
    for (int nt = 0; nt < 4; ++nt) {
#pragma unroll
      for (int r = 0; r < 4; ++r) {
        const int orow = wave * 128 + t * 16 + kg * 4 + r;
        const float mk = bf2f(mask_s[orow]);
        out[outbase + (size_t)orow * NL * DCM + nt * 16 + bcol] = (accO[nt][r] + bov[nt]) * mk;
      }
    }
  }
}

extern "C" void kernel_launch(void* const* d_in, const int* in_sizes, int n_in,
                              void* d_out, int out_size, void* d_ws, size_t ws_size,
                              hipStream_t stream) {
  (void)in_sizes; (void)n_in; (void)out_size; (void)ws_size;
  const float* m   = (const float*)d_in[0];
  const float* msk = (const float*)d_in[1];
  const float* lnw = (const float*)d_in[2];
  const float* lnb = (const float*)d_in[3];
  const float* wq  = (const float*)d_in[4];
  const float* wk  = (const float*)d_in[5];
  const float* wv  = (const float*)d_in[6];
  const float* wg  = (const float*)d_in[7];
  const float* bg  = (const float*)d_in[8];
  const float* wo  = (const float*)d_in[9];
  const float* bo  = (const float*)d_in[10];
  unsigned short* wt = (unsigned short*)d_ws;   // 8192 bf16 = 16 KB scratch
  float* out = (float*)d_out;

  prep_weights<<<dim3(16), dim3(256), 0, stream>>>(wg, wo, wt);
  fused<<<dim3(NB * NL), dim3(256), 0, stream>>>(
      m, msk, lnw, lnb, wq, wk, wv, wt, bg, bo, out);
}

// Round 4
// 69.933 us; speedup vs baseline: 2.7348x; 1.4415x over previous
//
#include <hip/hip_runtime.h>

#define NH 8
#define DCM 64
#define NB 2
#define NS 512
#define NL 384
#define LN_EPS 1e-5f
#define INV_SQRT_C 0.35355339059327379f

typedef __attribute__((ext_vector_type(8))) short short8v;   // 8 bf16 (4 VGPRs)
typedef __attribute__((ext_vector_type(4))) float f32x4;

__device__ __forceinline__ float4 ld4(const float* p) {
  return *reinterpret_cast<const float4*>(p);
}
__device__ __forceinline__ unsigned short f2bf(float f) {
  unsigned int b = __float_as_uint(f);
  b += 0x7FFFu + ((b >> 16) & 1u);          // round-to-nearest-even
  return (unsigned short)(b >> 16);
}
__device__ __forceinline__ float bf2f(unsigned short u) {
  return __uint_as_float(((unsigned int)u) << 16);
}

// ---------------------------------------------------------------------------
// Prep: wt[0..4095]=wg^T bf16 [n][k]; wt[4096..8191]=wo^T; wt[8192..12287]=wv^T.
// ---------------------------------------------------------------------------
__global__ void prep_weights(const float* __restrict__ wg,
                             const float* __restrict__ wo,
                             const float* __restrict__ wv,
                             unsigned short* __restrict__ wt) {
  int i = blockIdx.x * 256 + threadIdx.x;
  if (i < 4096) {
    int n = i >> 6, k = i & 63;
    wt[i]        = f2bf(wg[k * DCM + n]);
    wt[4096 + i] = f2bf(wo[k * DCM + n]);
    wt[8192 + i] = f2bf(wv[k * DCM + n]);
  }
}

// ---------------------------------------------------------------------------
// Fused: one WG per (b,l) column. m read ONCE from HBM.
//   P1: stream+LN (depth-4 prefetch) -> x bf16 LDS (swizzled) + masked sum -> qk
//   P2a: logits via MFMA -> p bf16 in P_T (swizzled) + sm partials
//   P2b: V = X@WV^T via MFMA, og += p*V in-lane -> og
//   P3: MFMA gating+output GEMMs -> out
// ---------------------------------------------------------------------------
__global__ __launch_bounds__(256) void fused(
    const float* __restrict__ m, const float* __restrict__ msk,
    const float* __restrict__ lnw, const float* __restrict__ lnb,
    const float* __restrict__ wq, const float* __restrict__ wk,
    const unsigned short* __restrict__ wt,
    const float* __restrict__ bg, const float* __restrict__ bo,
    float* __restrict__ out)
{
  const int col = blockIdx.x;              // b*NL + l
  const int b = col / NL, l = col % NL;
  const int tid = threadIdx.x;
  const int wave = tid >> 6, lane = tid & 63;

  __shared__ __align__(16) unsigned short x_lds[NS * DCM];   // 64 KB, swizzled
  __shared__ __align__(16) unsigned short mask_s[NS];        // 1 KB (0/1 exact)
  __shared__ __align__(16) unsigned char scratch[8192];      // red/P_T/a2t overlay
  __shared__ __align__(16) unsigned short qk_bf[16 * DCM];   // 2 KB, rows 8-15 = 0
  __shared__ float smred[4][8];
  __shared__ __align__(16) float ogred[4][DCM];
  __shared__ float og_s[DCM];

  float* redf = (float*)scratch;           // [4][64] @ 0..255
  float* dredf = redf + 256;               // 4
  float* qinf = redf + 272;                // 64 (16B aligned)
  float* qsf  = redf + 336;                // 64 (16B aligned)
  unsigned short* P_T = (unsigned short*)scratch;   // [8][512] bf16 in P2
  unsigned short* a2t = (unsigned short*)scratch;   // P3 transpose scratch

  for (int i = tid; i < NS; i += 256)
    mask_s[i] = f2bf(msk[(b * NS + i) * NL + l]);

  // ---------------- Phase 1: stream m once, LN, x->LDS bf16, masked sum ----
  const int c8 = lane & 7;          // channel block: cm = c8*8 .. c8*8+7
  const int r8 = lane >> 3;         // row within 8-row group
  float lw8[8], lb8[8];
#pragma unroll
  for (int k = 0; k < 8; ++k) { lw8[k] = lnw[c8 * 8 + k]; lb8[k] = lnb[c8 * 8 + k]; }
  __syncthreads();                  // mask_s ready (read inside P1 loop)

  float qacc[8] = {0.f,0.f,0.f,0.f,0.f,0.f,0.f,0.f};
  float dacc = 0.f;
  const int rowbase = wave * 128;
  {
    const size_t rstep = (size_t)8 * NL * DCM;
    const float* mb = m + ((size_t)b * NS * NL + l) * DCM + c8 * 8
                    + (size_t)(rowbase + r8) * NL * DCM;
    auto process = [&](const float4& A, const float4& Bv, int s) {
      float xv[8] = {A.x, A.y, A.z, A.w, Bv.x, Bv.y, Bv.z, Bv.w};
      float s1 = 0.f, s2 = 0.f;
#pragma unroll
      for (int k = 0; k < 8; ++k) { s1 += xv[k]; s2 += xv[k] * xv[k]; }
#pragma unroll
      for (int o = 1; o <= 4; o <<= 1) { s1 += __shfl_xor(s1, o); s2 += __shfl_xor(s2, o); }
      const float mu = s1 * 0.015625f;
      const float rs = rsqrtf(s2 * 0.015625f - mu * mu + LN_EPS);
      const float mk = bf2f(mask_s[s]);
      short8v xp;
#pragma unroll
      for (int k = 0; k < 8; ++k) {
        float xn = (xv[k] - mu) * rs * lw8[k] + lb8[k];
        xp[k] = (short)f2bf(xn);
        qacc[k] += xn * mk;
      }
      dacc += mk;
      *reinterpret_cast<short8v*>(&x_lds[s * DCM + ((c8 * 8) ^ ((s & 7) << 3))]) = xp;
    };
    // depth-4 prefetch, static register indexing
    float4 f0a = ld4(mb),             f0b = ld4(mb + 4);
    float4 f1a = ld4(mb + rstep),     f1b = ld4(mb + rstep + 4);
    float4 f2a = ld4(mb + 2 * rstep), f2b = ld4(mb + 2 * rstep + 4);
    float4 f3a = ld4(mb + 3 * rstep), f3b = ld4(mb + 3 * rstep + 4);
#pragma unroll
    for (int blk = 0; blk < 4; ++blk) {
      const int it0 = blk * 4;
      process(f0a, f0b, rowbase + (it0 + 0) * 8 + r8);
      if (blk < 3) { f0a = ld4(mb + (size_t)(it0 + 4) * rstep);
                     f0b = ld4(mb + (size_t)(it0 + 4) * rstep + 4); }
      process(f1a, f1b, rowbase + (it0 + 1) * 8 + r8);
      if (blk < 3) { f1a = ld4(mb + (size_t)(it0 + 5) * rstep);
                     f1b = ld4(mb + (size_t)(it0 + 5) * rstep + 4); }
      process(f2a, f2b, rowbase + (it0 + 2) * 8 + r8);
      if (blk < 3) { f2a = ld4(mb + (size_t)(it0 + 6) * rstep);
                     f2b = ld4(mb + (size_t)(it0 + 6) * rstep + 4); }
      process(f3a, f3b, rowbase + (it0 + 3) * 8 + r8);
      if (blk < 3) { f3a = ld4(mb + (size_t)(it0 + 7) * rstep);
                     f3b = ld4(mb + (size_t)(it0 + 7) * rstep + 4); }
    }
  }
#pragma unroll
  for (int o = 8; o <= 32; o <<= 1) {
#pragma unroll
    for (int k = 0; k < 8; ++k) qacc[k] += __shfl_xor(qacc[k], o);
    dacc += __shfl_xor(dacc, o);
  }
  if (lane < 8) {
    float4 t0; t0.x = qacc[0]; t0.y = qacc[1]; t0.z = qacc[2]; t0.w = qacc[3];
    float4 t1; t1.x = qacc[4]; t1.y = qacc[5]; t1.z = qacc[6]; t1.w = qacc[7];
    *reinterpret_cast<float4*>(&redf[wave * DCM + lane * 8])     = t0;
    *reinterpret_cast<float4*>(&redf[wave * DCM + lane * 8 + 4]) = t1;
  }
  // xor-reduce over {8,16,32} sums r8 only -> each row counted exactly once
  if (lane == 0) dredf[wave] = dacc;
  __syncthreads();

  if (tid < DCM) {
    float dn = fmaxf(dredf[0] + dredf[1] + dredf[2] + dredf[3], 1.0f);
    qinf[tid] = (redf[tid] + redf[DCM + tid] + redf[2 * DCM + tid] + redf[3 * DCM + tid]) / dn;
  }
  __syncthreads();
  if (tid < DCM) {
    float a = 0.f;
    for (int j = 0; j < DCM; ++j) a += qinf[j] * wq[j * DCM + tid];
    qsf[tid] = a;
  }
  __syncthreads();
  // qk_bf[h][cm] = (sum_c q[h*8+c]*wk[cm][h*8+c]) / sqrt(C), bf16; h>=8 -> 0
  for (int idx = tid; idx < 16 * DCM; idx += 256) {
    int h = idx >> 6, cm = idx & 63;
    float a = 0.f;
    if (h < NH) {
#pragma unroll
      for (int c = 0; c < 8; ++c) a += qsf[h * 8 + c] * wk[cm * DCM + h * 8 + c];
      a *= INV_SQRT_C;
    }
    qk_bf[idx] = f2bf(a);
  }
  __syncthreads();   // q-chain scratch dead; scratch becomes P_T

  // ---------------- Phase 2a: logits MFMA -> p bf16 in P_T, sm partials ----
  const int bcol = lane & 15;
  const int kg = lane >> 4;
  short8v qkB0 = *reinterpret_cast<const short8v*>(&qk_bf[bcol * DCM + kg * 8]);
  short8v qkB1 = *reinterpret_cast<const short8v*>(&qk_bf[bcol * DCM + 32 + kg * 8]);
  float smacc = 0.f;
  for (int t = 0; t < 8; ++t) {
    const int arow = wave * 128 + t * 16 + bcol;
    const int swz = (arow & 7) << 3;
    short8v a0 = *reinterpret_cast<const short8v*>(&x_lds[arow * DCM + ((kg * 8) ^ swz)]);
    short8v a1 = *reinterpret_cast<const short8v*>(&x_lds[arow * DCM + ((32 + kg * 8) ^ swz)]);
    f32x4 L = (f32x4){0.f, 0.f, 0.f, 0.f};
    L = __builtin_amdgcn_mfma_f32_16x16x32_bf16(a0, qkB0, L, 0, 0, 0);
    L = __builtin_amdgcn_mfma_f32_16x16x32_bf16(a1, qkB1, L, 0, 0, 0);
    const int s0 = wave * 128 + t * 16 + kg * 4;     // C rows = kg*4+r
    short4 mk4 = *reinterpret_cast<const short4*>(&mask_s[s0]);
    // logits are tiny (global query is a mean) -> exp without max-sub is safe
    float p0 = bf2f((unsigned short)mk4.x) * __expf(L[0]);
    float p1 = bf2f((unsigned short)mk4.y) * __expf(L[1]);
    float p2 = bf2f((unsigned short)mk4.z) * __expf(L[2]);
    float p3 = bf2f((unsigned short)mk4.w) * __expf(L[3]);
    smacc += (p0 + p1) + (p2 + p3);
    if (bcol < NH) {                                 // only real heads stored
      short4 pw;
      pw.x = (short)f2bf(p0); pw.y = (short)f2bf(p1);
      pw.z = (short)f2bf(p2); pw.w = (short)f2bf(p3);
      *reinterpret_cast<short4*>(&P_T[bcol * NS + (s0 ^ (bcol << 3))]) = pw;
    }
  }
  smacc += __shfl_xor(smacc, 16); smacc += __shfl_xor(smacc, 32);
  if (lane < NH) smred[wave][lane] = smacc;
  __syncthreads();

  // ---------------- Phase 2b: V=X@WV^T MFMA, og += p*V ---------------------
  short8v wvB[4][2];
#pragma unroll
  for (int nt = 0; nt < 4; ++nt)
#pragma unroll
    for (int kw = 0; kw < 2; ++kw)
      wvB[nt][kw] = *reinterpret_cast<const short8v*>(
          &wt[8192 + (nt * 16 + bcol) * DCM + kw * 32 + kg * 8]);
  float ogacc[4] = {0.f, 0.f, 0.f, 0.f};
  for (int t = 0; t < 8; ++t) {
    const int arow = wave * 128 + t * 16 + bcol;
    const int swz = (arow & 7) << 3;
    short8v a0 = *reinterpret_cast<const short8v*>(&x_lds[arow * DCM + ((kg * 8) ^ swz)]);
    short8v a1 = *reinterpret_cast<const short8v*>(&x_lds[arow * DCM + ((32 + kg * 8) ^ swz)]);
    const int s0 = wave * 128 + t * 16 + kg * 4;
#pragma unroll
    for (int nt = 0; nt < 4; ++nt) {
      f32x4 V = (f32x4){0.f, 0.f, 0.f, 0.f};
      V = __builtin_amdgcn_mfma_f32_16x16x32_bf16(a0, wvB[nt][0], V, 0, 0, 0);
      V = __builtin_amdgcn_mfma_f32_16x16x32_bf16(a1, wvB[nt][1], V, 0, 0, 0);
      const int h2 = 2 * nt + (bcol >> 3);           // head of this lane's col
      short4 p4 = *reinterpret_cast<const short4*>(&P_T[h2 * NS + (s0 ^ (h2 << 3))]);
      ogacc[nt] += bf2f((unsigned short)p4.x) * V[0]
                 + bf2f((unsigned short)p4.y) * V[1]
                 + bf2f((unsigned short)p4.z) * V[2]
                 + bf2f((unsigned short)p4.w) * V[3];
    }
  }
#pragma unroll
  for (int nt = 0; nt < 4; ++nt) {
    ogacc[nt] += __shfl_xor(ogacc[nt], 16);
    ogacc[nt] += __shfl_xor(ogacc[nt], 32);
  }
  if (lane < 16) {
#pragma unroll
    for (int nt = 0; nt < 4; ++nt) ogred[wave][nt * 16 + lane] = ogacc[nt];
  }
  __syncthreads();
  if (tid < DCM) {
    float smT = fmaxf(smred[0][tid >> 3] + smred[1][tid >> 3]
                    + smred[2][tid >> 3] + smred[3][tid >> 3], 1e-30f);
    og_s[tid] = (ogred[0][tid] + ogred[1][tid] + ogred[2][tid] + ogred[3][tid]) / smT;
  }
  __syncthreads();   // og ready; P_T dead -> scratch becomes a2t

  // ---------------- Phase 3: MFMA gating + output GEMMs --------------------
  short8v wgB[4][2], woB[4][2];
  float bgv[4], bov[4], ogv[4];
#pragma unroll
  for (int nt = 0; nt < 4; ++nt) {
    const int ncol = nt * 16 + bcol;
#pragma unroll
    for (int kw = 0; kw < 2; ++kw) {
      wgB[nt][kw] = *reinterpret_cast<const short8v*>(&wt[ncol * DCM + kw * 32 + kg * 8]);
      woB[nt][kw] = *reinterpret_cast<const short8v*>(&wt[4096 + ncol * DCM + kw * 32 + kg * 8]);
    }
    bgv[nt] = bg[ncol]; bov[nt] = bo[ncol]; ogv[nt] = og_s[ncol];
  }
  const size_t outbase = ((size_t)b * NS * NL + l) * DCM;
  unsigned short* a2w = &a2t[wave * 16 * DCM];

  for (int t = 0; t < 8; ++t) {
    const int arow = wave * 128 + t * 16 + bcol;
    const int swz = (arow & 7) << 3;
    short8v a0 = *reinterpret_cast<const short8v*>(&x_lds[arow * DCM + ((kg * 8) ^ swz)]);
    short8v a1 = *reinterpret_cast<const short8v*>(&x_lds[arow * DCM + ((32 + kg * 8) ^ swz)]);
    f32x4 accG[4];
#pragma unroll
    for (int nt = 0; nt < 4; ++nt) {
      accG[nt] = (f32x4){0.f, 0.f, 0.f, 0.f};
      accG[nt] = __builtin_amdgcn_mfma_f32_16x16x32_bf16(a0, wgB[nt][0], accG[nt], 0, 0, 0);
      accG[nt] = __builtin_amdgcn_mfma_f32_16x16x32_bf16(a1, wgB[nt][1], accG[nt], 0, 0, 0);
    }
    // sigmoid gate * og, write transposed bf16 (swizzled) to wave scratch
#pragma unroll
    for (int nt = 0; nt < 4; ++nt) {
      const int cc = nt * 16 + bcol;
#pragma unroll
      for (int r = 0; r < 4; ++r) {
        const int r2 = kg * 4 + r;                 // C-layout row
        float gx = accG[nt][r] + bgv[nt];
        float g = 1.0f / (1.0f + __expf(-gx));
        a2w[r2 * DCM + (cc ^ ((r2 & 7) << 3))] = f2bf(g * ogv[nt]);
      }
    }
    short8v b0 = *reinterpret_cast<const short8v*>(
        &a2w[bcol * DCM + ((kg * 8) ^ ((bcol & 7) << 3))]);
    short8v b1 = *reinterpret_cast<const short8v*>(
        &a2w[bcol * DCM + ((32 + kg * 8) ^ ((bcol & 7) << 3))]);
    f32x4 accO[4];
#pragma unroll
    for (int nt = 0; nt < 4; ++nt) {
      accO[nt] = (f32x4){0.f, 0.f, 0.f, 0.f};
      accO[nt] = __builtin_amdgcn_mfma_f32_16x16x32_bf16(b0, woB[nt][0], accO[nt], 0, 0, 0);
      accO[nt] = __builtin_amdgcn_mfma_f32_16x16x32_bf16(b1, woB[nt][1], accO[nt], 0, 0, 0);
    }
#pragma unroll
    for (int nt = 0; nt < 4; ++nt) {
#pragma unroll
      for (int r = 0; r < 4; ++r) {
        const int orow = wave * 128 + t * 16 + kg * 4 + r;
        const float mk = bf2f(mask_s[orow]);
        out[outbase + (size_t)orow * NL * DCM + nt * 16 + bcol] = (accO[nt][r] + bov[nt]) * mk;
      }
    }
  }
}

extern "C" void kernel_launch(void* const* d_in, const int* in_sizes, int n_in,
                              void* d_out, int out_size, void* d_ws, size_t ws_size,
                              hipStream_t stream) {
  (void)in_sizes; (void)n_in; (void)out_size; (void)ws_size;
  const float* m   = (const float*)d_in[0];
  const float* msk = (const float*)d_in[1];
  const float* lnw = (const float*)d_in[2];
  const float* lnb = (const float*)d_in[3];
  const float* wq  = (const float*)d_in[4];
  const float* wk  = (const float*)d_in[5];
  const float* wv  = (const float*)d_in[6];
  const float* wg  = (const float*)d_in[7];
  const float* bg  = (const float*)d_in[8];
  const float* wo  = (const float*)d_in[9];
  const float* bo  = (const float*)d_in[10];
  unsigned short* wt = (unsigned short*)d_ws;   // 12288 bf16 = 24 KB scratch
  float* out = (float*)d_out;

  prep_weights<<<dim3(16), dim3(256), 0, stream>>>(wg, wo, wv, wt);
  fused<<<dim3(NB * NL), dim3(256), 0, stream>>>(
      m, msk, lnw, lnb, wq, wk, wt, bg, bo, out);
}